// Round 19
// baseline (526.788 us; speedup 1.0000x reference)
//
#include <hip/hip_runtime.h>
#include <hip/hip_bf16.h>
#include <math.h>

#define NF 128          // feature width (both layers): 2 heads x 64
#define NBKT 256
#define BCAP 11264      // LDS csr window capacity (mean 9375, sd ~97)
#define SPANCAP 2048    // max keys per bucket (N up to ~174k)

typedef __attribute__((ext_vector_type(8))) short short8v;   // 8 bf16
typedef __attribute__((ext_vector_type(4))) float float4v;   // MFMA acc
typedef __attribute__((ext_vector_type(2))) float f32x2;     // packed f32 pair

__device__ inline float leaky02(float v) { return v >= 0.0f ? v : 0.2f * v; }

// fp32 -> bf16 round-to-nearest-even
__device__ inline unsigned short f2bf(float x) {
    unsigned u = __float_as_uint(x);
    u = u + 0x7fffu + ((u >> 16) & 1u);
    return (unsigned short)(u >> 16);
}
__device__ inline float bf2f(unsigned short h) {
    return __uint_as_float(((unsigned)h) << 16);
}
__device__ inline f32x2 mk2(float s) { return (f32x2){s, s}; }

// wave-uniform lane read -> SGPR (index must be wave-uniform)
__device__ inline int rl_i(int v, int lane) {
    return __builtin_amdgcn_readlane(v, lane);
}
__device__ inline float rl_f(float v, int lane) {
    return __uint_as_float(__builtin_amdgcn_readlane(__float_as_uint(v), lane));
}

// ---------------------------------------------------------------------------
// prep: (a) transposed bf16 W panels WT[m][col][k]; (b) attention projections
// P[m][f][c] = sum_d W[m][f][h][d]*a[h][d], c={el0,el1,er0,er1};
// (c) per-layer bias sums bs[layer][c] = sum_r b[r][c].  m = layer*3+r.
// ---------------------------------------------------------------------------
__global__ __launch_bounds__(256) void prep(
    const float* __restrict__ W1, const float* __restrict__ W2,
    const float* __restrict__ al1, const float* __restrict__ ar1,
    const float* __restrict__ b1,
    const float* __restrict__ al2, const float* __restrict__ ar2,
    const float* __restrict__ b2,
    unsigned short* __restrict__ WThi,
    float* __restrict__ P, float* __restrict__ bs)
{
    int i = blockIdx.x * 256 + threadIdx.x;
    if (i < 6 * 16384) {
        int m = i >> 14, rem = i & 16383, k = rem >> 7, col = rem & 127;
        const float* Wm = (m < 3) ? W1 + (size_t)m * 16384
                                  : W2 + (size_t)(m - 3) * 16384;
        WThi[(size_t)m * 16384 + col * 128 + k] = f2bf(Wm[k * 128 + col]);
    } else if (i < 6 * 16384 + 3072) {
        int idx = i - 6 * 16384;
        int m = idx >> 9, rem = idx & 511, f = rem >> 2, c = rem & 3;
        int head = c & 1;
        const float* Wm = (m < 3) ? W1 + (size_t)m * 16384
                                  : W2 + (size_t)(m - 3) * 16384;
        const float* vec;
        if (m < 3) vec = ((c < 2) ? al1 : ar1) + m * 128 + head * 64;
        else       vec = ((c < 2) ? al2 : ar2) + (m - 3) * 128 + head * 64;
        float s = 0.f;
        for (int d = 0; d < 64; d++) s += Wm[f * 128 + head * 64 + d] * vec[d];
        P[m * 512 + f * 4 + c] = s;
    } else if (i < 6 * 16384 + 3072 + 256) {
        int idx = i - 6 * 16384 - 3072;
        int layer = idx >> 7, cc = idx & 127;
        const float* b = layer ? b2 : b1;
        bs[layer * 128 + cc] = b[cc] + b[128 + cc] + b[256 + cc];
    }
}

// ---------------------------------------------------------------------------
// CSR build, bucketized. key = r*N + dst, bucket = key/span.
// ---------------------------------------------------------------------------
__global__ __launch_bounds__(256) void bucket_count(
    const int* __restrict__ dst, int* __restrict__ bcnt,
    int E, int N, int span)
{
    __shared__ int h[NBKT];
    h[threadIdx.x] = 0;
    __syncthreads();
    const int tot = 3 * E;
    for (int e = blockIdx.x * 256 + threadIdx.x; e < tot; e += gridDim.x * 256) {
        int r = (e >= 2 * E) ? 2 : (e >= E ? 1 : 0);
        int key = r * N + dst[e];
        atomicAdd(&h[key / span], 1);
    }
    __syncthreads();
    atomicAdd(&bcnt[threadIdx.x], h[threadIdx.x]);
}

// exclusive scan of 256 bucket counts -> bktbase[257], gtail; rowptr[n3]
__global__ __launch_bounds__(256) void scan256(
    const int* __restrict__ bcnt, int* __restrict__ bktbase,
    int* __restrict__ gtail, int* __restrict__ rowptr, int n3)
{
    __shared__ int s[256];
    int t = threadIdx.x;
    int v = bcnt[t];
    s[t] = v;
    __syncthreads();
    for (int off = 1; off < 256; off <<= 1) {
        int x = (t >= off) ? s[t - off] : 0;
        __syncthreads();
        s[t] += x;
        __syncthreads();
    }
    int excl = s[t] - v;
    bktbase[t] = excl;
    gtail[t] = excl;
    if (t == 255) { bktbase[256] = s[255]; rowptr[n3] = s[255]; }
}

// partition edges into bucket-ordered (key,src) pairs.
__global__ __launch_bounds__(256) void partition(
    const int* __restrict__ src, const int* __restrict__ dst,
    int* __restrict__ gtail, int2* __restrict__ pairs,
    int E, int N, int span)
{
    __shared__ int cnts[NBKT];
    __shared__ int gbase[NBKT];
    const int tot = 3 * E;
    const int per = (tot + gridDim.x - 1) / gridDim.x;
    const int e0 = blockIdx.x * per;
    const int e1 = min(tot, e0 + per);

    for (int tile = e0; tile < e1; tile += 2048) {
        int tend = min(e1, tile + 2048);
        cnts[threadIdx.x] = 0;
        __syncthreads();
        int myb[8], myoff[8], mykey[8], mysrc[8];
        int cnt_i = 0;
        for (int e = tile + threadIdx.x; e < tend; e += 256) {
            int r = (e >= 2 * E) ? 2 : (e >= E ? 1 : 0);
            int key = r * N + dst[e];
            int b = key / span;
            myb[cnt_i] = b; mykey[cnt_i] = key; mysrc[cnt_i] = src[e];
            myoff[cnt_i] = atomicAdd(&cnts[b], 1);
            cnt_i++;
        }
        __syncthreads();
        gbase[threadIdx.x] = atomicAdd(&gtail[threadIdx.x], cnts[threadIdx.x]);
        __syncthreads();
        for (int i = 0; i < cnt_i; i++)
            pairs[gbase[myb[i]] + myoff[i]] = make_int2(mykey[i], mysrc[i]);
        __syncthreads();
    }
}

// one block per bucket: LDS histogram -> LDS scan (emits rowptr slice)
// -> LDS placement -> coalesced window write.
__global__ __launch_bounds__(256) void place_build(
    const int2* __restrict__ pairs, const int* __restrict__ bktbase,
    int* __restrict__ rowptr, int* __restrict__ csr_src,
    int n3, int span)
{
    __shared__ int lbase[SPANCAP];
    __shared__ int acnt[SPANCAP];
    __shared__ int csr_l[BCAP];
    __shared__ int stot[256];

    const int b = blockIdx.x;
    const int t = threadIdx.x;
    const int klo = b * span;
    const int khi = min(n3, klo + span);
    const int kcount = khi - klo;
    if (kcount <= 0) return;
    const int p0 = bktbase[b], p1 = bktbase[b + 1];
    const int count = p1 - p0;

    for (int k = t; k < kcount; k += 256) lbase[k] = 0;
    __syncthreads();
    for (int i = t; i < count; i += 256)
        atomicAdd(&lbase[pairs[p0 + i].x - klo], 1);
    __syncthreads();

    const int kpt = (kcount + 255) / 256;
    const int my0 = t * kpt;
    int myn = kcount - my0;
    myn = myn < 0 ? 0 : (myn > kpt ? kpt : myn);
    int vals[8];
    int sum = 0;
    for (int i = 0; i < myn; i++) { vals[i] = lbase[my0 + i]; sum += vals[i]; }
    stot[t] = sum;
    __syncthreads();
    for (int off = 1; off < 256; off <<= 1) {
        int x = (t >= off) ? stot[t - off] : 0;
        __syncthreads();
        stot[t] += x;
        __syncthreads();
    }
    int run = stot[t] - sum;
    for (int i = 0; i < myn; i++) {
        lbase[my0 + i] = run;
        rowptr[klo + my0 + i] = p0 + run;
        run += vals[i];
    }
    for (int k = t; k < kcount; k += 256) acnt[k] = 0;
    __syncthreads();

    if (count <= BCAP) {
        for (int i = t; i < count; i += 256) {
            int2 kv = pairs[p0 + i];
            int k = kv.x - klo;
            int pos = lbase[k] + atomicAdd(&acnt[k], 1);
            csr_l[pos] = kv.y;
        }
        __syncthreads();
        for (int i = t; i < count; i += 256)
            csr_src[p0 + i] = csr_l[i];
    } else {
        for (int i = t; i < count; i += 256) {
            int2 kv = pairs[p0 + i];
            int k = kv.x - klo;
            int pos = p0 + lbase[k] + atomicAdd(&acnt[k], 1);
            csr_src[pos] = kv.y;
        }
    }
}

// ---------------------------------------------------------------------------
// elproj (layer 1 only): elr[n][12] = x . P  and Xb bf16 interleaved copy
// ---------------------------------------------------------------------------
__global__ __launch_bounds__(256) void elproj(
    const float* __restrict__ Xin, const float* __restrict__ P,
    float* __restrict__ elr, unsigned short* __restrict__ Xb, int n)
{
    __shared__ float Xs[16][128];
    __shared__ float Ps[1536];
    int t = threadIdx.x;
    int n0 = blockIdx.x * 16;

    for (int i = t; i < 1536; i += 256) Ps[i] = P[i];
    {
        int row = t >> 4, cb = (t & 15) * 8;
        int gn = n0 + row;
        float4 a = make_float4(0, 0, 0, 0), b = make_float4(0, 0, 0, 0);
        if (gn < n) {
            a = *(const float4*)(Xin + (size_t)gn * 128 + cb);
            b = *(const float4*)(Xin + (size_t)gn * 128 + cb + 4);
        }
        *(float4*)&Xs[row][cb]     = a;
        *(float4*)&Xs[row][cb + 4] = b;
    }
    __syncthreads();

    if (t < 192) {
        int nl = t / 12, c = t % 12, r = c >> 2, j = c & 3;
        int gn = n0 + nl;
        if (gn < n) {
            float sum = 0.f;
            for (int k = 0; k < 128; k++)
                sum += Xs[nl][k] * Ps[r * 512 + k * 4 + j];
            elr[(size_t)gn * 12 + c] = sum;
        }
    }
    {
        int row = t >> 4, db = (t & 15) * 4;
        int gn = n0 + row;
        if (gn < n) {
#pragma unroll
            for (int i2 = 0; i2 < 4; i2++) {
                int d = db + i2;
                ushort2 v;
                v.x = f2bf(Xs[row][d]);
                v.y = f2bf(Xs[row][64 + d]);
                *(ushort2*)(Xb + (size_t)gn * 128 + 2 * d) = v;
            }
        }
    }
}

// ---------------------------------------------------------------------------
// aggregate3: ALL 3 relations per node in one kernel. Wave per node.
// Phase 1: 12 interleaved shuffle-reduce chains (4-step span for deg<=16,
// 98.8% of nodes); fast-rcp for the softmax divides. Phase 2: readlane
// broadcast + SGPR-base gather; packed f32x2 FMA (2 pk_fma per edge-rel).
// Fallback (any deg>64): per-relation chunked path.
// ---------------------------------------------------------------------------
__global__ __launch_bounds__(256) void aggregate3(
    const int* __restrict__ rowptr, const int* __restrict__ csr_src,
    const float* __restrict__ elr, const unsigned short* __restrict__ Xb,
    unsigned short* __restrict__ Xag0, unsigned short* __restrict__ Xag1,
    unsigned short* __restrict__ Xag2, int n)
{
    int node = (int)((blockIdx.x * 256 + threadIdx.x) >> 6);
    int lane = threadIdx.x & 63;
    if (node >= n) return;

    int beg0 = rowptr[node],         end0 = rowptr[node + 1];
    int beg1 = rowptr[n + node],     end1 = rowptr[n + node + 1];
    int beg2 = rowptr[2 * n + node], end2 = rowptr[2 * n + node + 1];
    int deg0 = end0 - beg0, deg1 = end1 - beg1, deg2 = end2 - beg2;

    const float* erp = elr + (size_t)node * 12;
    float er00 = erp[2],  er01 = erp[3];
    float er10 = erp[6],  er11 = erp[7];
    float er20 = erp[10], er21 = erp[11];

    // packed accumulators: {head0, head0'} is wrong — pairing is
    // {featA(lane), featB(64+lane)} per head: A0={a000,a001} etc.
    f32x2 A0 = mk2(0.f), A1 = mk2(0.f);
    f32x2 B0 = mk2(0.f), B1 = mk2(0.f);
    f32x2 C0 = mk2(0.f), C1 = mk2(0.f);

    int degmax = max(deg0, max(deg1, deg2));

    if (degmax <= 64) {
        // ---- phase 1: weights for all 3 relations, interleaved
        int s0 = 0, s1 = 0, s2 = 0;
        if (lane < deg0) s0 = csr_src[beg0 + lane];
        if (lane < deg1) s1 = csr_src[beg1 + lane];
        if (lane < deg2) s2 = csr_src[beg2 + lane];
        float v00 = -INFINITY, v01 = -INFINITY;
        float v10 = -INFINITY, v11 = -INFINITY;
        float v20 = -INFINITY, v21 = -INFINITY;
        if (lane < deg0) {
            float2 e = *(const float2*)(elr + (size_t)s0 * 12);
            v00 = leaky02(e.x + er00); v01 = leaky02(e.y + er01);
        }
        if (lane < deg1) {
            float2 e = *(const float2*)(elr + (size_t)s1 * 12 + 4);
            v10 = leaky02(e.x + er10); v11 = leaky02(e.y + er11);
        }
        if (lane < deg2) {
            float2 e = *(const float2*)(elr + (size_t)s2 * 12 + 8);
            v20 = leaky02(e.x + er20); v21 = leaky02(e.y + er21);
        }
        float M00 = v00, M01 = v01, M10 = v10, M11 = v11, M20 = v20, M21 = v21;
        const int topoff = (degmax <= 16) ? 8 : 32;   // 4-step vs 6-step span
#pragma unroll 6
        for (int off = 32; off; off >>= 1) {
            if (off > topoff) continue;
            M00 = fmaxf(M00, __shfl_xor(M00, off, 64));
            M01 = fmaxf(M01, __shfl_xor(M01, off, 64));
            M10 = fmaxf(M10, __shfl_xor(M10, off, 64));
            M11 = fmaxf(M11, __shfl_xor(M11, off, 64));
            M20 = fmaxf(M20, __shfl_xor(M20, off, 64));
            M21 = fmaxf(M21, __shfl_xor(M21, off, 64));
        }
        float x00 = (lane < deg0) ? __expf(v00 - M00) : 0.f;
        float x01 = (lane < deg0) ? __expf(v01 - M01) : 0.f;
        float x10 = (lane < deg1) ? __expf(v10 - M10) : 0.f;
        float x11 = (lane < deg1) ? __expf(v11 - M11) : 0.f;
        float x20 = (lane < deg2) ? __expf(v20 - M20) : 0.f;
        float x21 = (lane < deg2) ? __expf(v21 - M21) : 0.f;
        float S00 = x00, S01 = x01, S10 = x10, S11 = x11, S20 = x20, S21 = x21;
#pragma unroll 6
        for (int off = 32; off; off >>= 1) {
            if (off > topoff) continue;
            S00 += __shfl_xor(S00, off, 64);
            S01 += __shfl_xor(S01, off, 64);
            S10 += __shfl_xor(S10, off, 64);
            S11 += __shfl_xor(S11, off, 64);
            S20 += __shfl_xor(S20, off, 64);
            S21 += __shfl_xor(S21, off, 64);
        }
        // fast reciprocal (~1 ulp) instead of full-precision divide
        float w00 = x00 * __builtin_amdgcn_rcpf(S00);
        float w01 = x01 * __builtin_amdgcn_rcpf(S01);
        float w10 = x10 * __builtin_amdgcn_rcpf(S10);
        float w11 = x11 * __builtin_amdgcn_rcpf(S11);
        float w20 = x20 * __builtin_amdgcn_rcpf(S20);
        float w21 = x21 * __builtin_amdgcn_rcpf(S21);

        // ---- phase 2: readlane broadcast + SGPR-base gather + pk FMA
        const char* XbB = (const char*)Xb;
        const unsigned int voff = 4u * (unsigned)lane;
        for (int j0 = 0; j0 < degmax; j0 += 4) {
            unsigned int g0[4], g1[4], g2[4];
            float p00[4], p01[4], p10[4], p11[4], p20[4], p21[4];
#pragma unroll
            for (int j = 0; j < 4; j++) {
                int e = j0 + j;          // wave-uniform
                if (e < deg0) {
                    int ss = rl_i(s0, e);
                    p00[j] = rl_f(w00, e);
                    p01[j] = rl_f(w01, e);
                    g0[j] = *(const unsigned int*)(XbB + (size_t)ss * 256 + voff);
                }
                if (e < deg1) {
                    int ss = rl_i(s1, e);
                    p10[j] = rl_f(w10, e);
                    p11[j] = rl_f(w11, e);
                    g1[j] = *(const unsigned int*)(XbB + (size_t)ss * 256 + voff);
                }
                if (e < deg2) {
                    int ss = rl_i(s2, e);
                    p20[j] = rl_f(w20, e);
                    p21[j] = rl_f(w21, e);
                    g2[j] = *(const unsigned int*)(XbB + (size_t)ss * 256 + voff);
                }
            }
#pragma unroll
            for (int j = 0; j < 4; j++) {
                int e = j0 + j;
                if (e < deg0) {
                    f32x2 xv = (f32x2){__uint_as_float(g0[j] << 16),
                                       __uint_as_float(g0[j] & 0xffff0000u)};
                    A0 += mk2(p00[j]) * xv;
                    A1 += mk2(p01[j]) * xv;
                }
                if (e < deg1) {
                    f32x2 xv = (f32x2){__uint_as_float(g1[j] << 16),
                                       __uint_as_float(g1[j] & 0xffff0000u)};
                    B0 += mk2(p10[j]) * xv;
                    B1 += mk2(p11[j]) * xv;
                }
                if (e < deg2) {
                    f32x2 xv = (f32x2){__uint_as_float(g2[j] << 16),
                                       __uint_as_float(g2[j] & 0xffff0000u)};
                    C0 += mk2(p20[j]) * xv;
                    C1 += mk2(p21[j]) * xv;
                }
            }
        }
    } else {
        // ---- rare fallback: chunked per-relation (deg may exceed 64)
#pragma unroll
        for (int r = 0; r < 3; r++) {
            int beg = (r == 0) ? beg0 : (r == 1) ? beg1 : beg2;
            int end = (r == 0) ? end0 : (r == 1) ? end1 : end2;
            if (beg >= end) continue;
            int roff = r * 4;
            float er0 = (r == 0) ? er00 : (r == 1) ? er10 : er20;
            float er1 = (r == 0) ? er01 : (r == 1) ? er11 : er21;
            float m0 = -INFINITY, m1 = -INFINITY, d0 = 0.f, d1 = 0.f;
            for (int c0 = beg; c0 < end; c0 += 64) {
                int i = c0 + lane;
                float v0 = -INFINITY, v1 = -INFINITY;
                if (i < end) {
                    int s = csr_src[i];
                    float2 e = *(const float2*)(elr + (size_t)s * 12 + roff);
                    v0 = leaky02(e.x + er0);
                    v1 = leaky02(e.y + er1);
                }
                float M0 = v0, M1 = v1;
#pragma unroll
                for (int off = 32; off; off >>= 1) {
                    M0 = fmaxf(M0, __shfl_xor(M0, off, 64));
                    M1 = fmaxf(M1, __shfl_xor(M1, off, 64));
                }
                float x0 = (i < end) ? __expf(v0 - M0) : 0.f;
                float x1 = (i < end) ? __expf(v1 - M1) : 0.f;
                float S0 = x0, S1 = x1;
#pragma unroll
                for (int off = 32; off; off >>= 1) {
                    S0 += __shfl_xor(S0, off, 64);
                    S1 += __shfl_xor(S1, off, 64);
                }
                float nm0 = fmaxf(m0, M0), nm1 = fmaxf(m1, M1);
                d0 = d0 * __expf(m0 - nm0) + S0 * __expf(M0 - nm0);
                d1 = d1 * __expf(m1 - nm1) + S1 * __expf(M1 - nm1);
                m0 = nm0; m1 = nm1;
            }
            float inv0 = 1.f / d0, inv1 = 1.f / d1;
            float b00 = 0.f, b01 = 0.f, b10 = 0.f, b11 = 0.f;
            for (int c0 = beg; c0 < end; c0 += 64) {
                int i = c0 + lane;
                int cn = min(64, end - c0);
                int s = 0; float w0 = 0.f, w1 = 0.f;
                if (i < end) {
                    s = csr_src[i];
                    float2 e = *(const float2*)(elr + (size_t)s * 12 + roff);
                    w0 = __expf(leaky02(e.x + er0) - m0) * inv0;
                    w1 = __expf(leaky02(e.y + er1) - m1) * inv1;
                }
                for (int j = 0; j < cn; j++) {
                    int ss    = __shfl(s, j, 64);
                    float ww0 = __shfl(w0, j, 64);
                    float ww1 = __shfl(w1, j, 64);
                    ushort2 xv = *(const ushort2*)(Xb + (size_t)ss * 128 + 2 * lane);
                    float xa = bf2f(xv.x), xb = bf2f(xv.y);
                    b00 += ww0 * xa; b01 += ww0 * xb;
                    b10 += ww1 * xa; b11 += ww1 * xb;
                }
            }
            if (r == 0) { A0 = (f32x2){b00, b01}; A1 = (f32x2){b10, b11}; }
            else if (r == 1) { B0 = (f32x2){b00, b01}; B1 = (f32x2){b10, b11}; }
            else { C0 = (f32x2){b00, b01}; C1 = (f32x2){b10, b11}; }
        }
    }

    unsigned short* x0 = Xag0 + (size_t)node * 256;
    x0[lane]       = f2bf(A0[0]);
    x0[64 + lane]  = f2bf(A0[1]);
    x0[128 + lane] = f2bf(A1[0]);
    x0[192 + lane] = f2bf(A1[1]);
    unsigned short* x1 = Xag1 + (size_t)node * 256;
    x1[lane]       = f2bf(B0[0]);
    x1[64 + lane]  = f2bf(B0[1]);
    x1[128 + lane] = f2bf(B1[0]);
    x1[192 + lane] = f2bf(B1[1]);
    unsigned short* x2 = Xag2 + (size_t)node * 256;
    x2[lane]       = f2bf(C0[0]);
    x2[64 + lane]  = f2bf(C0[1]);
    x2[128 + lane] = f2bf(C1[0]);
    x2[192 + lane] = f2bf(C1[1]);
}

// ---------------------------------------------------------------------------
// Fused 3-relation MFMA GEMM per layer, single-bf16 W in LDS (32 KB).
// 512 threads = 8 waves, 128 rows/block. Per relation: stage W panel into
// LDS once per block (XOR-swizzled); A-fragments read DIRECTLY from global
// Xag_r. acc accumulates all 3 relations; h never exists in HBM.
// ---------------------------------------------------------------------------
__global__ __launch_bounds__(512) void gemm3(
    const unsigned short* __restrict__ Xag0,
    const unsigned short* __restrict__ Xag1,
    const unsigned short* __restrict__ Xag2,
    const unsigned short* __restrict__ WThi,
    const float* __restrict__ bs,      // [128] layer bias sums
    const float* __restrict__ Pn,      // next-layer P (1536), layer1 only
    float* __restrict__ elrO, unsigned short* __restrict__ XbO,  // layer1 out
    float* __restrict__ out,           // layer2 out
    int n, int layer2)
{
    __shared__ short Wl[16384];        // 32KB, swizzled rows
    __shared__ float Ps[1536];
    __shared__ float bsS[128];
    const int t    = threadIdx.x;
    const int row0 = blockIdx.x * 128;

    if (!layer2) for (int i = t; i < 1536; i += 512) Ps[i] = Pn[i];
    if (t < 128) bsS[t] = bs[t];

    const int w  = t >> 6;       // wave 0..7 -> rows w*16..w*16+15
    const int l  = t & 63;
    const int lr = l & 15;
    const int lq = l >> 4;
    const int myrow = row0 + w * 16 + lr;
    const int arow  = min(myrow, n - 1);

    float4v acc[8];
#pragma unroll
    for (int g = 0; g < 8; g++) acc[g] = (float4v){0.f, 0.f, 0.f, 0.f};

#pragma unroll
    for (int r = 0; r < 3; r++) {
        const unsigned short* WhG = WThi + (size_t)r * 16384;
        const unsigned short* Xa  = (r == 0) ? Xag0 : (r == 1) ? Xag1 : Xag2;

        __syncthreads();   // previous relation's W reads done
        // stage W: 2048 16B-chunks / 512 threads = 4 iters, coalesced
        for (int i = t; i < 2048; i += 512) {
            int row  = i >> 4, k16 = i & 15;
            short8v v = *(const short8v*)(WhG + i * 8);
            int off = row * 256 + ((k16 * 16) ^ ((row & 7) << 4));
            *(short8v*)((char*)Wl + off) = v;
        }
        __syncthreads();

        const unsigned short* xrow = Xa + (size_t)arow * 256;
        short8v a0[4], a1[4];
#pragma unroll
        for (int ks = 0; ks < 4; ks++) {
            a0[ks] = *(const short8v*)(xrow + ks * 32 + lq * 8);        // head 0
            a1[ks] = *(const short8v*)(xrow + 128 + ks * 32 + lq * 8);  // head 1
        }
#pragma unroll
        for (int ks = 0; ks < 4; ks++) {
#pragma unroll
            for (int g = 0; g < 8; g++) {
                int woff = (g * 16 + lr) * 256 +
                           ((ks * 64 + lq * 16) ^ ((lr & 7) << 4));
                short8v bh = *(const short8v*)((char*)Wl + woff);
                short8v xx = (g < 4) ? a0[ks] : a1[ks];
                acc[g] = __builtin_amdgcn_mfma_f32_16x16x32_bf16(xx, bh, acc[g], 0, 0, 0);
            }
        }
    }

    float bsv[8];
#pragma unroll
    for (int g = 0; g < 8; g++) bsv[g] = bsS[g * 16 + lr];

    if (!layer2) {
#pragma unroll
        for (int rr = 0; rr < 4; rr++) {
            int gr = row0 + w * 16 + lq * 4 + rr;
            if (gr >= n) continue;
            float hr[8];
#pragma unroll
            for (int g = 0; g < 8; g++)
                hr[g] = fmaxf(acc[g][rr] + bsv[g], 0.f);
            unsigned short* xo = XbO + (size_t)gr * 128;
#pragma unroll
            for (int g = 0; g < 4; g++) {
                ushort2 v; v.x = f2bf(hr[g]); v.y = f2bf(hr[g + 4]);
                *(ushort2*)(xo + 2 * (g * 16 + lr)) = v;
            }
            float ev[12];
#pragma unroll
            for (int c = 0; c < 12; c++) {
                int r3 = c >> 2, j = c & 3;
                float s = 0.f;
#pragma unroll
                for (int g = 0; g < 8; g++)
                    s += hr[g] * Ps[r3 * 512 + (g * 16 + lr) * 4 + j];
                ev[c] = s;
            }
#pragma unroll
            for (int off = 1; off < 16; off <<= 1) {
#pragma unroll
                for (int c = 0; c < 12; c++)
                    ev[c] += __shfl_xor(ev[c], off, 64);
            }
            if (lr == 0) {
                float* eo = elrO + (size_t)gr * 12;
                *(float4*)(eo)     = make_float4(ev[0], ev[1], ev[2], ev[3]);
                *(float4*)(eo + 4) = make_float4(ev[4], ev[5], ev[6], ev[7]);
                *(float4*)(eo + 8) = make_float4(ev[8], ev[9], ev[10], ev[11]);
            }
        }
    } else {
#pragma unroll
        for (int rr = 0; rr < 4; rr++) {
            int gr = row0 + w * 16 + lq * 4 + rr;
            if (gr >= n) continue;
#pragma unroll
            for (int g = 0; g < 4; g++) {
                out[(size_t)gr * 64 + g * 16 + lr] =
                    0.5f * (acc[g][rr] + acc[g + 4][rr] + bsv[g] + bsv[g + 4]);
            }
        }
    }
}

// ---------------------------------------------------------------------------
extern "C" void kernel_launch(void* const* d_in, const int* in_sizes, int n_in,
                              void* d_out, int out_size, void* d_ws, size_t ws_size,
                              hipStream_t stream)
{
    const float* x   = (const float*)d_in[0];
    const int*   src = (const int*)  d_in[1];
    const int*   dst = (const int*)  d_in[2];
    const float* W1  = (const float*)d_in[3];
    const float* al1 = (const float*)d_in[4];
    const float* ar1 = (const float*)d_in[5];
    const float* b1  = (const float*)d_in[6];
    const float* W2  = (const float*)d_in[7];
    const float* al2 = (const float*)d_in[8];
    const float* ar2 = (const float*)d_in[9];
    const float* b2  = (const float*)d_in[10];

    const int N = in_sizes[0] / NF;          // 100000
    const int E = in_sizes[1] / 3;           // 800000

    char* p = (char*)d_ws;
    unsigned short* Xag0 = (unsigned short*)p; p += (size_t)N * 256 * 2;
    unsigned short* Xag1 = (unsigned short*)p; p += (size_t)N * 256 * 2;
    unsigned short* Xag2 = (unsigned short*)p; p += (size_t)N * 256 * 2;
    unsigned short* XbA  = (unsigned short*)p; p += (size_t)N * 128 * 2;
    unsigned short* XbB  = (unsigned short*)p; p += (size_t)N * 128 * 2;
    float* elrA = (float*)p;                   p += (size_t)N * 12 * 4;
    float* elrB = (float*)p;                   p += (size_t)N * 12 * 4;
    unsigned short* WThi = (unsigned short*)p; p += 6 * 16384 * 2;
    float* P  = (float*)p;                     p += 6 * 512 * 4;
    float* bs = (float*)p;                     p += 256 * 4;
    int* rowptr  = (int*)p;                    p += ((size_t)3 * N + 1) * 4;
    int* csr_src = (int*)p;                    p += (size_t)3 * E * 4;
    // CSR-build scratch aliased onto Xag0 (build completes before the first
    // aggregate writes Xag0; rebuilt from inputs every call -> replay-safe).
    int* bcnt    = (int*)Xag0;                 // 256
    int* bktbase = bcnt + 256;                 // 257 (pad to 288)
    int* gtail   = bktbase + 288;              // 256
    int2* pairs  = (int2*)(gtail + 256);       // 3E (19.2 MB, fits in Xag0)

    const int n3 = 3 * N;
    const int span = (n3 + NBKT - 1) / NBKT;

    prep<<<(6 * 16384 + 3072 + 256 + 255) / 256, 256, 0, stream>>>(
        W1, W2, al1, ar1, b1, al2, ar2, b2, WThi, P, bs);

    hipMemsetAsync(bcnt, 0, 256 * 4, stream);
    bucket_count<<<512, 256, 0, stream>>>(dst, bcnt, E, N, span);
    scan256<<<1, 256, 0, stream>>>(bcnt, bktbase, gtail, rowptr, n3);
    partition<<<512, 256, 0, stream>>>(src, dst, gtail, pairs, E, N, span);
    place_build<<<NBKT, 256, 0, stream>>>(pairs, bktbase, rowptr, csr_src,
                                          n3, span);

    const int aggBlocks  = (N + 3) / 4;
    const int gemmBlocks = (N + 127) / 128;
    const int projBlocks = (N + 15) / 16;

    // ---------------- layer 1 ----------------
    elproj<<<projBlocks, 256, 0, stream>>>(x, P, elrA, XbA, N);
    aggregate3<<<aggBlocks, 256, 0, stream>>>(
        rowptr, csr_src, elrA, XbA, Xag0, Xag1, Xag2, N);
    gemm3<<<gemmBlocks, 512, 0, stream>>>(
        Xag0, Xag1, Xag2, WThi, bs, P + 1536,
        elrB, XbB, nullptr, N, 0);

    // ---------------- layer 2 ----------------
    aggregate3<<<aggBlocks, 256, 0, stream>>>(
        rowptr, csr_src, elrB, XbB, Xag0, Xag1, Xag2, N);
    gemm3<<<gemmBlocks, 512, 0, stream>>>(
        Xag0, Xag1, Xag2, WThi + 3 * 16384, bs + 128, nullptr,
        nullptr, nullptr, (float*)d_out, N, 1);
}

// Round 20
// 501.455 us; speedup vs baseline: 1.0505x; 1.0505x over previous
//
#include <hip/hip_runtime.h>
#include <hip/hip_bf16.h>
#include <math.h>

#define NF 128          // feature width (both layers): 2 heads x 64
#define NBKT 256
#define BCAP 11264      // LDS csr window capacity (mean 9375, sd ~97)
#define SPANCAP 2048    // max keys per bucket (N up to ~174k)

typedef __attribute__((ext_vector_type(8))) short short8v;   // 8 bf16
typedef __attribute__((ext_vector_type(4))) float float4v;   // MFMA acc

__device__ inline float leaky02(float v) { return v >= 0.0f ? v : 0.2f * v; }

// fp32 -> bf16 round-to-nearest-even
__device__ inline unsigned short f2bf(float x) {
    unsigned u = __float_as_uint(x);
    u = u + 0x7fffu + ((u >> 16) & 1u);
    return (unsigned short)(u >> 16);
}
__device__ inline float bf2f(unsigned short h) {
    return __uint_as_float(((unsigned)h) << 16);
}

// wave-uniform lane read -> SGPR (index must be wave-uniform)
__device__ inline int rl_i(int v, int lane) {
    return __builtin_amdgcn_readlane(v, lane);
}
__device__ inline float rl_f(float v, int lane) {
    return __uint_as_float(__builtin_amdgcn_readlane(__float_as_uint(v), lane));
}

// ---------------------------------------------------------------------------
// prep: (a) transposed bf16 W panels WT[m][col][k]; (b) attention projections
// P[m][f][c] = sum_d W[m][f][h][d]*a[h][d], c={el0,el1,er0,er1};
// (c) per-layer bias sums bs[layer][c] = sum_r b[r][c].  m = layer*3+r.
// ---------------------------------------------------------------------------
__global__ __launch_bounds__(256) void prep(
    const float* __restrict__ W1, const float* __restrict__ W2,
    const float* __restrict__ al1, const float* __restrict__ ar1,
    const float* __restrict__ b1,
    const float* __restrict__ al2, const float* __restrict__ ar2,
    const float* __restrict__ b2,
    unsigned short* __restrict__ WThi,
    float* __restrict__ P, float* __restrict__ bs)
{
    int i = blockIdx.x * 256 + threadIdx.x;
    if (i < 6 * 16384) {
        int m = i >> 14, rem = i & 16383, k = rem >> 7, col = rem & 127;
        const float* Wm = (m < 3) ? W1 + (size_t)m * 16384
                                  : W2 + (size_t)(m - 3) * 16384;
        WThi[(size_t)m * 16384 + col * 128 + k] = f2bf(Wm[k * 128 + col]);
    } else if (i < 6 * 16384 + 3072) {
        int idx = i - 6 * 16384;
        int m = idx >> 9, rem = idx & 511, f = rem >> 2, c = rem & 3;
        int head = c & 1;
        const float* Wm = (m < 3) ? W1 + (size_t)m * 16384
                                  : W2 + (size_t)(m - 3) * 16384;
        const float* vec;
        if (m < 3) vec = ((c < 2) ? al1 : ar1) + m * 128 + head * 64;
        else       vec = ((c < 2) ? al2 : ar2) + (m - 3) * 128 + head * 64;
        float s = 0.f;
        for (int d = 0; d < 64; d++) s += Wm[f * 128 + head * 64 + d] * vec[d];
        P[m * 512 + f * 4 + c] = s;
    } else if (i < 6 * 16384 + 3072 + 256) {
        int idx = i - 6 * 16384 - 3072;
        int layer = idx >> 7, cc = idx & 127;
        const float* b = layer ? b2 : b1;
        bs[layer * 128 + cc] = b[cc] + b[128 + cc] + b[256 + cc];
    }
}

// ---------------------------------------------------------------------------
// CSR build, bucketized. key = r*N + dst, bucket = key/span.
// ---------------------------------------------------------------------------
__global__ __launch_bounds__(256) void bucket_count(
    const int* __restrict__ dst, int* __restrict__ bcnt,
    int E, int N, int span)
{
    __shared__ int h[NBKT];
    h[threadIdx.x] = 0;
    __syncthreads();
    const int tot = 3 * E;
    for (int e = blockIdx.x * 256 + threadIdx.x; e < tot; e += gridDim.x * 256) {
        int r = (e >= 2 * E) ? 2 : (e >= E ? 1 : 0);
        int key = r * N + dst[e];
        atomicAdd(&h[key / span], 1);
    }
    __syncthreads();
    atomicAdd(&bcnt[threadIdx.x], h[threadIdx.x]);
}

// exclusive scan of 256 bucket counts -> bktbase[257], gtail; rowptr[n3]
__global__ __launch_bounds__(256) void scan256(
    const int* __restrict__ bcnt, int* __restrict__ bktbase,
    int* __restrict__ gtail, int* __restrict__ rowptr, int n3)
{
    __shared__ int s[256];
    int t = threadIdx.x;
    int v = bcnt[t];
    s[t] = v;
    __syncthreads();
    for (int off = 1; off < 256; off <<= 1) {
        int x = (t >= off) ? s[t - off] : 0;
        __syncthreads();
        s[t] += x;
        __syncthreads();
    }
    int excl = s[t] - v;
    bktbase[t] = excl;
    gtail[t] = excl;
    if (t == 255) { bktbase[256] = s[255]; rowptr[n3] = s[255]; }
}

// partition edges into bucket-ordered (key,src) pairs.
__global__ __launch_bounds__(256) void partition(
    const int* __restrict__ src, const int* __restrict__ dst,
    int* __restrict__ gtail, int2* __restrict__ pairs,
    int E, int N, int span)
{
    __shared__ int cnts[NBKT];
    __shared__ int gbase[NBKT];
    const int tot = 3 * E;
    const int per = (tot + gridDim.x - 1) / gridDim.x;
    const int e0 = blockIdx.x * per;
    const int e1 = min(tot, e0 + per);

    for (int tile = e0; tile < e1; tile += 2048) {
        int tend = min(e1, tile + 2048);
        cnts[threadIdx.x] = 0;
        __syncthreads();
        int myb[8], myoff[8], mykey[8], mysrc[8];
        int cnt_i = 0;
        for (int e = tile + threadIdx.x; e < tend; e += 256) {
            int r = (e >= 2 * E) ? 2 : (e >= E ? 1 : 0);
            int key = r * N + dst[e];
            int b = key / span;
            myb[cnt_i] = b; mykey[cnt_i] = key; mysrc[cnt_i] = src[e];
            myoff[cnt_i] = atomicAdd(&cnts[b], 1);
            cnt_i++;
        }
        __syncthreads();
        gbase[threadIdx.x] = atomicAdd(&gtail[threadIdx.x], cnts[threadIdx.x]);
        __syncthreads();
        for (int i = 0; i < cnt_i; i++)
            pairs[gbase[myb[i]] + myoff[i]] = make_int2(mykey[i], mysrc[i]);
        __syncthreads();
    }
}

// one block per bucket: LDS histogram -> LDS scan (emits rowptr slice)
// -> LDS placement -> coalesced window write.
__global__ __launch_bounds__(256) void place_build(
    const int2* __restrict__ pairs, const int* __restrict__ bktbase,
    int* __restrict__ rowptr, int* __restrict__ csr_src,
    int n3, int span)
{
    __shared__ int lbase[SPANCAP];
    __shared__ int acnt[SPANCAP];
    __shared__ int csr_l[BCAP];
    __shared__ int stot[256];

    const int b = blockIdx.x;
    const int t = threadIdx.x;
    const int klo = b * span;
    const int khi = min(n3, klo + span);
    const int kcount = khi - klo;
    if (kcount <= 0) return;
    const int p0 = bktbase[b], p1 = bktbase[b + 1];
    const int count = p1 - p0;

    for (int k = t; k < kcount; k += 256) lbase[k] = 0;
    __syncthreads();
    for (int i = t; i < count; i += 256)
        atomicAdd(&lbase[pairs[p0 + i].x - klo], 1);
    __syncthreads();

    const int kpt = (kcount + 255) / 256;
    const int my0 = t * kpt;
    int myn = kcount - my0;
    myn = myn < 0 ? 0 : (myn > kpt ? kpt : myn);
    int vals[8];
    int sum = 0;
    for (int i = 0; i < myn; i++) { vals[i] = lbase[my0 + i]; sum += vals[i]; }
    stot[t] = sum;
    __syncthreads();
    for (int off = 1; off < 256; off <<= 1) {
        int x = (t >= off) ? stot[t - off] : 0;
        __syncthreads();
        stot[t] += x;
        __syncthreads();
    }
    int run = stot[t] - sum;
    for (int i = 0; i < myn; i++) {
        lbase[my0 + i] = run;
        rowptr[klo + my0 + i] = p0 + run;
        run += vals[i];
    }
    for (int k = t; k < kcount; k += 256) acnt[k] = 0;
    __syncthreads();

    if (count <= BCAP) {
        for (int i = t; i < count; i += 256) {
            int2 kv = pairs[p0 + i];
            int k = kv.x - klo;
            int pos = lbase[k] + atomicAdd(&acnt[k], 1);
            csr_l[pos] = kv.y;
        }
        __syncthreads();
        for (int i = t; i < count; i += 256)
            csr_src[p0 + i] = csr_l[i];
    } else {
        for (int i = t; i < count; i += 256) {
            int2 kv = pairs[p0 + i];
            int k = kv.x - klo;
            int pos = p0 + lbase[k] + atomicAdd(&acnt[k], 1);
            csr_src[pos] = kv.y;
        }
    }
}

// ---------------------------------------------------------------------------
// elproj (layer 1 only): elr[n][12] = x . P  and Xb bf16 interleaved copy
// ---------------------------------------------------------------------------
__global__ __launch_bounds__(256) void elproj(
    const float* __restrict__ Xin, const float* __restrict__ P,
    float* __restrict__ elr, unsigned short* __restrict__ Xb, int n)
{
    __shared__ float Xs[16][128];
    __shared__ float Ps[1536];
    int t = threadIdx.x;
    int n0 = blockIdx.x * 16;

    for (int i = t; i < 1536; i += 256) Ps[i] = P[i];
    {
        int row = t >> 4, cb = (t & 15) * 8;
        int gn = n0 + row;
        float4 a = make_float4(0, 0, 0, 0), b = make_float4(0, 0, 0, 0);
        if (gn < n) {
            a = *(const float4*)(Xin + (size_t)gn * 128 + cb);
            b = *(const float4*)(Xin + (size_t)gn * 128 + cb + 4);
        }
        *(float4*)&Xs[row][cb]     = a;
        *(float4*)&Xs[row][cb + 4] = b;
    }
    __syncthreads();

    if (t < 192) {
        int nl = t / 12, c = t % 12, r = c >> 2, j = c & 3;
        int gn = n0 + nl;
        if (gn < n) {
            float sum = 0.f;
            for (int k = 0; k < 128; k++)
                sum += Xs[nl][k] * Ps[r * 512 + k * 4 + j];
            elr[(size_t)gn * 12 + c] = sum;
        }
    }
    {
        int row = t >> 4, db = (t & 15) * 4;
        int gn = n0 + row;
        if (gn < n) {
#pragma unroll
            for (int i2 = 0; i2 < 4; i2++) {
                int d = db + i2;
                ushort2 v;
                v.x = f2bf(Xs[row][d]);
                v.y = f2bf(Xs[row][64 + d]);
                *(ushort2*)(Xb + (size_t)gn * 128 + 2 * d) = v;
            }
        }
    }
}

// ---------------------------------------------------------------------------
// aggregate3: ALL 3 relations per node in one kernel. Wave per node.
// Phase 1: 12 interleaved shuffle-reduce chains (4-step span for deg<=16,
// 98.8% of nodes; 6-step for deg<=64); fast-rcp softmax normalize.
// Phase 2: readlane broadcast -> SGPRs, SGPR-base gather, scalar FMAs
// (measured-best form). Fallback (any deg>64): per-relation chunked path.
// ---------------------------------------------------------------------------
__global__ __launch_bounds__(256) void aggregate3(
    const int* __restrict__ rowptr, const int* __restrict__ csr_src,
    const float* __restrict__ elr, const unsigned short* __restrict__ Xb,
    unsigned short* __restrict__ Xag0, unsigned short* __restrict__ Xag1,
    unsigned short* __restrict__ Xag2, int n)
{
    int node = (int)((blockIdx.x * 256 + threadIdx.x) >> 6);
    int lane = threadIdx.x & 63;
    if (node >= n) return;

    int beg0 = rowptr[node],         end0 = rowptr[node + 1];
    int beg1 = rowptr[n + node],     end1 = rowptr[n + node + 1];
    int beg2 = rowptr[2 * n + node], end2 = rowptr[2 * n + node + 1];
    int deg0 = end0 - beg0, deg1 = end1 - beg1, deg2 = end2 - beg2;

    const float* erp = elr + (size_t)node * 12;
    float er00 = erp[2],  er01 = erp[3];
    float er10 = erp[6],  er11 = erp[7];
    float er20 = erp[10], er21 = erp[11];

    float a000 = 0.f, a001 = 0.f, a010 = 0.f, a011 = 0.f;
    float a100 = 0.f, a101 = 0.f, a110 = 0.f, a111 = 0.f;
    float a200 = 0.f, a201 = 0.f, a210 = 0.f, a211 = 0.f;

    int degmax = max(deg0, max(deg1, deg2));

    if (degmax <= 64) {
        // ---- phase 1: weights for all 3 relations, interleaved
        int s0 = 0, s1 = 0, s2 = 0;
        if (lane < deg0) s0 = csr_src[beg0 + lane];
        if (lane < deg1) s1 = csr_src[beg1 + lane];
        if (lane < deg2) s2 = csr_src[beg2 + lane];
        float v00 = -INFINITY, v01 = -INFINITY;
        float v10 = -INFINITY, v11 = -INFINITY;
        float v20 = -INFINITY, v21 = -INFINITY;
        if (lane < deg0) {
            float2 e = *(const float2*)(elr + (size_t)s0 * 12);
            v00 = leaky02(e.x + er00); v01 = leaky02(e.y + er01);
        }
        if (lane < deg1) {
            float2 e = *(const float2*)(elr + (size_t)s1 * 12 + 4);
            v10 = leaky02(e.x + er10); v11 = leaky02(e.y + er11);
        }
        if (lane < deg2) {
            float2 e = *(const float2*)(elr + (size_t)s2 * 12 + 8);
            v20 = leaky02(e.x + er20); v21 = leaky02(e.y + er21);
        }
        float M00 = v00, M01 = v01, M10 = v10, M11 = v11, M20 = v20, M21 = v21;
        const int topoff = (degmax <= 16) ? 8 : 32;   // 4-step vs 6-step span
#pragma unroll 6
        for (int off = 32; off; off >>= 1) {
            if (off > topoff) continue;
            M00 = fmaxf(M00, __shfl_xor(M00, off, 64));
            M01 = fmaxf(M01, __shfl_xor(M01, off, 64));
            M10 = fmaxf(M10, __shfl_xor(M10, off, 64));
            M11 = fmaxf(M11, __shfl_xor(M11, off, 64));
            M20 = fmaxf(M20, __shfl_xor(M20, off, 64));
            M21 = fmaxf(M21, __shfl_xor(M21, off, 64));
        }
        float x00 = (lane < deg0) ? __expf(v00 - M00) : 0.f;
        float x01 = (lane < deg0) ? __expf(v01 - M01) : 0.f;
        float x10 = (lane < deg1) ? __expf(v10 - M10) : 0.f;
        float x11 = (lane < deg1) ? __expf(v11 - M11) : 0.f;
        float x20 = (lane < deg2) ? __expf(v20 - M20) : 0.f;
        float x21 = (lane < deg2) ? __expf(v21 - M21) : 0.f;
        float S00 = x00, S01 = x01, S10 = x10, S11 = x11, S20 = x20, S21 = x21;
#pragma unroll 6
        for (int off = 32; off; off >>= 1) {
            if (off > topoff) continue;
            S00 += __shfl_xor(S00, off, 64);
            S01 += __shfl_xor(S01, off, 64);
            S10 += __shfl_xor(S10, off, 64);
            S11 += __shfl_xor(S11, off, 64);
            S20 += __shfl_xor(S20, off, 64);
            S21 += __shfl_xor(S21, off, 64);
        }
        // fast reciprocal (~1 ulp) instead of full-precision divide
        float w00 = x00 * __builtin_amdgcn_rcpf(S00);
        float w01 = x01 * __builtin_amdgcn_rcpf(S01);
        float w10 = x10 * __builtin_amdgcn_rcpf(S10);
        float w11 = x11 * __builtin_amdgcn_rcpf(S11);
        float w20 = x20 * __builtin_amdgcn_rcpf(S20);
        float w21 = x21 * __builtin_amdgcn_rcpf(S21);

        // ---- phase 2: readlane broadcast + SGPR-base gather (scalar FMA)
        const char* XbB = (const char*)Xb;
        const unsigned int voff = 4u * (unsigned)lane;
        for (int j0 = 0; j0 < degmax; j0 += 4) {
            unsigned int g0[4], g1[4], g2[4];
            float p00[4], p01[4], p10[4], p11[4], p20[4], p21[4];
#pragma unroll
            for (int j = 0; j < 4; j++) {
                int e = j0 + j;          // wave-uniform
                if (e < deg0) {
                    int ss = rl_i(s0, e);
                    p00[j] = rl_f(w00, e);
                    p01[j] = rl_f(w01, e);
                    g0[j] = *(const unsigned int*)(XbB + (size_t)ss * 256 + voff);
                }
                if (e < deg1) {
                    int ss = rl_i(s1, e);
                    p10[j] = rl_f(w10, e);
                    p11[j] = rl_f(w11, e);
                    g1[j] = *(const unsigned int*)(XbB + (size_t)ss * 256 + voff);
                }
                if (e < deg2) {
                    int ss = rl_i(s2, e);
                    p20[j] = rl_f(w20, e);
                    p21[j] = rl_f(w21, e);
                    g2[j] = *(const unsigned int*)(XbB + (size_t)ss * 256 + voff);
                }
            }
#pragma unroll
            for (int j = 0; j < 4; j++) {
                int e = j0 + j;
                if (e < deg0) {
                    float xa = __uint_as_float(g0[j] << 16);
                    float xb = __uint_as_float(g0[j] & 0xffff0000u);
                    a000 = fmaf(p00[j], xa, a000); a001 = fmaf(p00[j], xb, a001);
                    a010 = fmaf(p01[j], xa, a010); a011 = fmaf(p01[j], xb, a011);
                }
                if (e < deg1) {
                    float xa = __uint_as_float(g1[j] << 16);
                    float xb = __uint_as_float(g1[j] & 0xffff0000u);
                    a100 = fmaf(p10[j], xa, a100); a101 = fmaf(p10[j], xb, a101);
                    a110 = fmaf(p11[j], xa, a110); a111 = fmaf(p11[j], xb, a111);
                }
                if (e < deg2) {
                    float xa = __uint_as_float(g2[j] << 16);
                    float xb = __uint_as_float(g2[j] & 0xffff0000u);
                    a200 = fmaf(p20[j], xa, a200); a201 = fmaf(p20[j], xb, a201);
                    a210 = fmaf(p21[j], xa, a210); a211 = fmaf(p21[j], xb, a211);
                }
            }
        }
    } else {
        // ---- rare fallback: chunked per-relation (deg may exceed 64)
#pragma unroll
        for (int r = 0; r < 3; r++) {
            int beg = (r == 0) ? beg0 : (r == 1) ? beg1 : beg2;
            int end = (r == 0) ? end0 : (r == 1) ? end1 : end2;
            if (beg >= end) continue;
            int roff = r * 4;
            float er0 = (r == 0) ? er00 : (r == 1) ? er10 : er20;
            float er1 = (r == 0) ? er01 : (r == 1) ? er11 : er21;
            float m0 = -INFINITY, m1 = -INFINITY, d0 = 0.f, d1 = 0.f;
            for (int c0 = beg; c0 < end; c0 += 64) {
                int i = c0 + lane;
                float v0 = -INFINITY, v1 = -INFINITY;
                if (i < end) {
                    int s = csr_src[i];
                    float2 e = *(const float2*)(elr + (size_t)s * 12 + roff);
                    v0 = leaky02(e.x + er0);
                    v1 = leaky02(e.y + er1);
                }
                float M0 = v0, M1 = v1;
#pragma unroll
                for (int off = 32; off; off >>= 1) {
                    M0 = fmaxf(M0, __shfl_xor(M0, off, 64));
                    M1 = fmaxf(M1, __shfl_xor(M1, off, 64));
                }
                float x0 = (i < end) ? __expf(v0 - M0) : 0.f;
                float x1 = (i < end) ? __expf(v1 - M1) : 0.f;
                float S0 = x0, S1 = x1;
#pragma unroll
                for (int off = 32; off; off >>= 1) {
                    S0 += __shfl_xor(S0, off, 64);
                    S1 += __shfl_xor(S1, off, 64);
                }
                float nm0 = fmaxf(m0, M0), nm1 = fmaxf(m1, M1);
                d0 = d0 * __expf(m0 - nm0) + S0 * __expf(M0 - nm0);
                d1 = d1 * __expf(m1 - nm1) + S1 * __expf(M1 - nm1);
                m0 = nm0; m1 = nm1;
            }
            float inv0 = 1.f / d0, inv1 = 1.f / d1;
            float b00 = 0.f, b01 = 0.f, b10 = 0.f, b11 = 0.f;
            for (int c0 = beg; c0 < end; c0 += 64) {
                int i = c0 + lane;
                int cn = min(64, end - c0);
                int s = 0; float w0 = 0.f, w1 = 0.f;
                if (i < end) {
                    s = csr_src[i];
                    float2 e = *(const float2*)(elr + (size_t)s * 12 + roff);
                    w0 = __expf(leaky02(e.x + er0) - m0) * inv0;
                    w1 = __expf(leaky02(e.y + er1) - m1) * inv1;
                }
                for (int j = 0; j < cn; j++) {
                    int ss    = __shfl(s, j, 64);
                    float ww0 = __shfl(w0, j, 64);
                    float ww1 = __shfl(w1, j, 64);
                    ushort2 xv = *(const ushort2*)(Xb + (size_t)ss * 128 + 2 * lane);
                    float xa = bf2f(xv.x), xb = bf2f(xv.y);
                    b00 += ww0 * xa; b01 += ww0 * xb;
                    b10 += ww1 * xa; b11 += ww1 * xb;
                }
            }
            if (r == 0) { a000 = b00; a001 = b01; a010 = b10; a011 = b11; }
            else if (r == 1) { a100 = b00; a101 = b01; a110 = b10; a111 = b11; }
            else { a200 = b00; a201 = b01; a210 = b10; a211 = b11; }
        }
    }

    unsigned short* x0 = Xag0 + (size_t)node * 256;
    x0[lane]       = f2bf(a000);
    x0[64 + lane]  = f2bf(a001);
    x0[128 + lane] = f2bf(a010);
    x0[192 + lane] = f2bf(a011);
    unsigned short* x1 = Xag1 + (size_t)node * 256;
    x1[lane]       = f2bf(a100);
    x1[64 + lane]  = f2bf(a101);
    x1[128 + lane] = f2bf(a110);
    x1[192 + lane] = f2bf(a111);
    unsigned short* x2 = Xag2 + (size_t)node * 256;
    x2[lane]       = f2bf(a200);
    x2[64 + lane]  = f2bf(a201);
    x2[128 + lane] = f2bf(a210);
    x2[192 + lane] = f2bf(a211);
}

// ---------------------------------------------------------------------------
// Fused 3-relation MFMA GEMM per layer, single-bf16 W in LDS (32 KB).
// 512 threads = 8 waves, 128 rows/block. Per relation: stage W panel into
// LDS once per block (XOR-swizzled); A-fragments read DIRECTLY from global
// Xag_r. acc accumulates all 3 relations; h never exists in HBM.
// ---------------------------------------------------------------------------
__global__ __launch_bounds__(512) void gemm3(
    const unsigned short* __restrict__ Xag0,
    const unsigned short* __restrict__ Xag1,
    const unsigned short* __restrict__ Xag2,
    const unsigned short* __restrict__ WThi,
    const float* __restrict__ bs,      // [128] layer bias sums
    const float* __restrict__ Pn,      // next-layer P (1536), layer1 only
    float* __restrict__ elrO, unsigned short* __restrict__ XbO,  // layer1 out
    float* __restrict__ out,           // layer2 out
    int n, int layer2)
{
    __shared__ short Wl[16384];        // 32KB, swizzled rows
    __shared__ float Ps[1536];
    __shared__ float bsS[128];
    const int t    = threadIdx.x;
    const int row0 = blockIdx.x * 128;

    if (!layer2) for (int i = t; i < 1536; i += 512) Ps[i] = Pn[i];
    if (t < 128) bsS[t] = bs[t];

    const int w  = t >> 6;       // wave 0..7 -> rows w*16..w*16+15
    const int l  = t & 63;
    const int lr = l & 15;
    const int lq = l >> 4;
    const int myrow = row0 + w * 16 + lr;
    const int arow  = min(myrow, n - 1);

    float4v acc[8];
#pragma unroll
    for (int g = 0; g < 8; g++) acc[g] = (float4v){0.f, 0.f, 0.f, 0.f};

#pragma unroll
    for (int r = 0; r < 3; r++) {
        const unsigned short* WhG = WThi + (size_t)r * 16384;
        const unsigned short* Xa  = (r == 0) ? Xag0 : (r == 1) ? Xag1 : Xag2;

        __syncthreads();   // previous relation's W reads done
        // stage W: 2048 16B-chunks / 512 threads = 4 iters, coalesced
        for (int i = t; i < 2048; i += 512) {
            int row  = i >> 4, k16 = i & 15;
            short8v v = *(const short8v*)(WhG + i * 8);
            int off = row * 256 + ((k16 * 16) ^ ((row & 7) << 4));
            *(short8v*)((char*)Wl + off) = v;
        }
        __syncthreads();

        const unsigned short* xrow = Xa + (size_t)arow * 256;
        short8v a0[4], a1[4];
#pragma unroll
        for (int ks = 0; ks < 4; ks++) {
            a0[ks] = *(const short8v*)(xrow + ks * 32 + lq * 8);        // head 0
            a1[ks] = *(const short8v*)(xrow + 128 + ks * 32 + lq * 8);  // head 1
        }
#pragma unroll
        for (int ks = 0; ks < 4; ks++) {
#pragma unroll
            for (int g = 0; g < 8; g++) {
                int woff = (g * 16 + lr) * 256 +
                           ((ks * 64 + lq * 16) ^ ((lr & 7) << 4));
                short8v bh = *(const short8v*)((char*)Wl + woff);
                short8v xx = (g < 4) ? a0[ks] : a1[ks];
                acc[g] = __builtin_amdgcn_mfma_f32_16x16x32_bf16(xx, bh, acc[g], 0, 0, 0);
            }
        }
    }

    float bsv[8];
#pragma unroll
    for (int g = 0; g < 8; g++) bsv[g] = bsS[g * 16 + lr];

    if (!layer2) {
#pragma unroll
        for (int rr = 0; rr < 4; rr++) {
            int gr = row0 + w * 16 + lq * 4 + rr;
            if (gr >= n) continue;
            float hr[8];
#pragma unroll
            for (int g = 0; g < 8; g++)
                hr[g] = fmaxf(acc[g][rr] + bsv[g], 0.f);
            unsigned short* xo = XbO + (size_t)gr * 128;
#pragma unroll
            for (int g = 0; g < 4; g++) {
                ushort2 v; v.x = f2bf(hr[g]); v.y = f2bf(hr[g + 4]);
                *(ushort2*)(xo + 2 * (g * 16 + lr)) = v;
            }
            float ev[12];
#pragma unroll
            for (int c = 0; c < 12; c++) {
                int r3 = c >> 2, j = c & 3;
                float s = 0.f;
#pragma unroll
                for (int g = 0; g < 8; g++)
                    s += hr[g] * Ps[r3 * 512 + (g * 16 + lr) * 4 + j];
                ev[c] = s;
            }
#pragma unroll
            for (int off = 1; off < 16; off <<= 1) {
#pragma unroll
                for (int c = 0; c < 12; c++)
                    ev[c] += __shfl_xor(ev[c], off, 64);
            }
            if (lr == 0) {
                float* eo = elrO + (size_t)gr * 12;
                *(float4*)(eo)     = make_float4(ev[0], ev[1], ev[2], ev[3]);
                *(float4*)(eo + 4) = make_float4(ev[4], ev[5], ev[6], ev[7]);
                *(float4*)(eo + 8) = make_float4(ev[8], ev[9], ev[10], ev[11]);
            }
        }
    } else {
#pragma unroll
        for (int rr = 0; rr < 4; rr++) {
            int gr = row0 + w * 16 + lq * 4 + rr;
            if (gr >= n) continue;
#pragma unroll
            for (int g = 0; g < 4; g++) {
                out[(size_t)gr * 64 + g * 16 + lr] =
                    0.5f * (acc[g][rr] + acc[g + 4][rr] + bsv[g] + bsv[g + 4]);
            }
        }
    }
}

// ---------------------------------------------------------------------------
extern "C" void kernel_launch(void* const* d_in, const int* in_sizes, int n_in,
                              void* d_out, int out_size, void* d_ws, size_t ws_size,
                              hipStream_t stream)
{
    const float* x   = (const float*)d_in[0];
    const int*   src = (const int*)  d_in[1];
    const int*   dst = (const int*)  d_in[2];
    const float* W1  = (const float*)d_in[3];
    const float* al1 = (const float*)d_in[4];
    const float* ar1 = (const float*)d_in[5];
    const float* b1  = (const float*)d_in[6];
    const float* W2  = (const float*)d_in[7];
    const float* al2 = (const float*)d_in[8];
    const float* ar2 = (const float*)d_in[9];
    const float* b2  = (const float*)d_in[10];

    const int N = in_sizes[0] / NF;          // 100000
    const int E = in_sizes[1] / 3;           // 800000

    char* p = (char*)d_ws;
    unsigned short* Xag0 = (unsigned short*)p; p += (size_t)N * 256 * 2;
    unsigned short* Xag1 = (unsigned short*)p; p += (size_t)N * 256 * 2;
    unsigned short* Xag2 = (unsigned short*)p; p += (size_t)N * 256 * 2;
    unsigned short* XbA  = (unsigned short*)p; p += (size_t)N * 128 * 2;
    unsigned short* XbB  = (unsigned short*)p; p += (size_t)N * 128 * 2;
    float* elrA = (float*)p;                   p += (size_t)N * 12 * 4;
    float* elrB = (float*)p;                   p += (size_t)N * 12 * 4;
    unsigned short* WThi = (unsigned short*)p; p += 6 * 16384 * 2;
    float* P  = (float*)p;                     p += 6 * 512 * 4;
    float* bs = (float*)p;                     p += 256 * 4;
    int* rowptr  = (int*)p;                    p += ((size_t)3 * N + 1) * 4;
    int* csr_src = (int*)p;                    p += (size_t)3 * E * 4;
    // CSR-build scratch aliased onto Xag0 (build completes before the first
    // aggregate writes Xag0; rebuilt from inputs every call -> replay-safe).
    int* bcnt    = (int*)Xag0;                 // 256
    int* bktbase = bcnt + 256;                 // 257 (pad to 288)
    int* gtail   = bktbase + 288;              // 256
    int2* pairs  = (int2*)(gtail + 256);       // 3E (19.2 MB, fits in Xag0)

    const int n3 = 3 * N;
    const int span = (n3 + NBKT - 1) / NBKT;

    prep<<<(6 * 16384 + 3072 + 256 + 255) / 256, 256, 0, stream>>>(
        W1, W2, al1, ar1, b1, al2, ar2, b2, WThi, P, bs);

    hipMemsetAsync(bcnt, 0, 256 * 4, stream);
    bucket_count<<<512, 256, 0, stream>>>(dst, bcnt, E, N, span);
    scan256<<<1, 256, 0, stream>>>(bcnt, bktbase, gtail, rowptr, n3);
    partition<<<512, 256, 0, stream>>>(src, dst, gtail, pairs, E, N, span);
    place_build<<<NBKT, 256, 0, stream>>>(pairs, bktbase, rowptr, csr_src,
                                          n3, span);

    const int aggBlocks  = (N + 3) / 4;
    const int gemmBlocks = (N + 127) / 128;
    const int projBlocks = (N + 15) / 16;

    // ---------------- layer 1 ----------------
    elproj<<<projBlocks, 256, 0, stream>>>(x, P, elrA, XbA, N);
    aggregate3<<<aggBlocks, 256, 0, stream>>>(
        rowptr, csr_src, elrA, XbA, Xag0, Xag1, Xag2, N);
    gemm3<<<gemmBlocks, 512, 0, stream>>>(
        Xag0, Xag1, Xag2, WThi, bs, P + 1536,
        elrB, XbB, nullptr, N, 0);

    // ---------------- layer 2 ----------------
    aggregate3<<<aggBlocks, 256, 0, stream>>>(
        rowptr, csr_src, elrB, XbB, Xag0, Xag1, Xag2, N);
    gemm3<<<gemmBlocks, 512, 0, stream>>>(
        Xag0, Xag1, Xag2, WThi + 3 * 16384, bs + 128, nullptr,
        nullptr, nullptr, (float*)d_out, N, 1);
}